// Round 1
// baseline (123.960 us; speedup 1.0000x reference)
//
#include <hip/hip_runtime.h>
#include <hip/hip_bf16.h>

#define ALPHA 100.0f

// Per-triangle precomputed invariants: 6 x float4 = 96 B
//  q0: v0.xyz, flag(area ok ? 1 : 0)
//  q1: e0.xyz, dot00
//  q2: e1.xyz, dot11
//  q3: n.xyz,  dot01
//  q4: inv_denom, inv00, inv11, c12(=dot00-dot01)
//  q5: abab(=dot00-2dot01+dot11), invab, 0, 0

__global__ __launch_bounds__(256) void rast_pre(const float* __restrict__ tv,
                                                float4* __restrict__ pre) {
    int i = blockIdx.x * 256 + threadIdx.x;   // 0..4095 triangles (4 batches x 1024)
    if (i >= 4096) return;
    const float* t = tv + (size_t)i * 9;
    float v0x = t[0], v0y = t[1], v0z = t[2];
    float v1x = t[3], v1y = t[4], v1z = t[5];
    float v2x = t[6], v2y = t[7], v2z = t[8];

    float e0x = v1x - v0x, e0y = v1y - v0y, e0z = v1z - v0z;
    float e1x = v2x - v0x, e1y = v2y - v0y, e1z = v2z - v0z;

    float nx = e0y * e1z - e0z * e1y;
    float ny = e0z * e1x - e0x * e1z;
    float nz = e0x * e1y - e0y * e1x;
    float area2 = nx * nx + ny * ny + nz * nz;

    float dot00 = e0x * e0x + e0y * e0y + e0z * e0z;
    float dot01 = e0x * e1x + e0y * e1y + e0z * e1z;
    float dot11 = e1x * e1x + e1y * e1y + e1z * e1z;

    float denom     = fmaxf(area2, 1e-12f);
    float inv_denom = 1.0f / denom;
    float inv00     = 1.0f / fmaxf(dot00, 1e-12f);
    float inv11     = 1.0f / fmaxf(dot11, 1e-12f);
    float abab      = dot00 - 2.0f * dot01 + dot11;
    float invab     = 1.0f / fmaxf(abab, 1e-12f);
    float flag      = (area2 >= 4e-10f) ? 1.0f : 0.0f;   // 4 * (1e-5)^2
    float c12       = dot00 - dot01;

    float4* q = pre + (size_t)i * 6;
    q[0] = make_float4(v0x, v0y, v0z, flag);
    q[1] = make_float4(e0x, e0y, e0z, dot00);
    q[2] = make_float4(e1x, e1y, e1z, dot11);
    q[3] = make_float4(nx, ny, nz, dot01);
    q[4] = make_float4(inv_denom, inv00, inv11, c12);
    q[5] = make_float4(abab, invab, 0.0f, 0.0f);
}

// Grid: 512 blocks x 256 threads.
// block -> (batch = blockIdx>>7, point-block = blockIdx&127 -> 64 points)
// lane (0..63) = point within block; wave (0..3) = triangle chunk of 256.
__global__ __launch_bounds__(256) void rast_main(const float* __restrict__ pts,
                                                 const float4* __restrict__ pre,
                                                 float* __restrict__ out) {
    int b    = blockIdx.x >> 7;
    int pblk = blockIdx.x & 127;
    int lane = threadIdx.x & 63;
    int wave = __builtin_amdgcn_readfirstlane((int)(threadIdx.x >> 6));

    int point = pblk * 64 + lane;
    const float* pp = pts + ((size_t)b * 8192 + point) * 3;
    float px = pp[0], py = pp[1], pz = pp[2];

    const float4* tp = pre + ((size_t)b * 1024 + (size_t)wave * 256) * 6;

    float dmin = 3.4e38f;
#pragma unroll 2
    for (int k = 0; k < 256; ++k) {
        float4 q0 = tp[0];
        float4 q1 = tp[1];
        float4 q2 = tp[2];
        float4 q3 = tp[3];
        float4 q4 = tp[4];
        float4 q5 = tp[5];
        tp += 6;

        float dx = px - q0.x, dy = py - q0.y, dz = pz - q0.z;
        float dd = dx * dx + dy * dy + dz * dz;
        float a0 = q1.x * dx + q1.y * dy + q1.z * dz;   // dot(e0, d)
        float a1 = q2.x * dx + q2.y * dy + q2.z * dz;   // dot(e1, d)
        float dn = q3.x * dx + q3.y * dy + q3.z * dz;   // dot(n, d)

        float dot00 = q1.w, dot11 = q2.w, dot01 = q3.w;
        float inv_denom = q4.x, inv00 = q4.y, inv11 = q4.z, c12 = q4.w;
        float abab = q5.x, invab = q5.y, flag = q0.w;

        float u = (dot11 * a0 - dot01 * a1) * inv_denom;
        float v = (dot00 * a1 - dot01 * a0) * inv_denom;
        float w = 1.0f - u - v;
        float plane = dn * dn * inv_denom;

        float a02 = a0 + a0;
        // segment v0-v1
        float t1 = fminf(fmaxf(a0 * inv00, 0.0f), 1.0f);
        float s1 = dd + t1 * (t1 * dot00 - a02);
        // segment v0-v2
        float a12 = a1 + a1;
        float t2 = fminf(fmaxf(a1 * inv11, 0.0f), 1.0f);
        float s2 = dd + t2 * (t2 * dot11 - a12);
        // segment v1-v2
        float pab  = c12 + a1 - a0;           // dot(p-v1, v2-v1)
        float papa = (dd - a02) + dot00;      // |p-v1|^2
        float t3 = fminf(fmaxf(pab * invab, 0.0f), 1.0f);
        float s3 = papa + t3 * (t3 * abab - (pab + pab));

        float edge = fminf(s1, fminf(s2, s3));
        bool inside = (fminf(fminf(u, v), w) >= 0.0f) && (flag > 0.5f);
        float r = inside ? plane : edge;
        dmin = fminf(dmin, r);
    }

    __shared__ float red[256];
    red[threadIdx.x] = dmin;
    __syncthreads();
    if (threadIdx.x < 64) {
        float m = fminf(fminf(red[threadIdx.x], red[threadIdx.x + 64]),
                        fminf(red[threadIdx.x + 128], red[threadIdx.x + 192]));
        out[(size_t)b * 8192 + pblk * 64 + threadIdx.x] = __expf(-ALPHA * m);
    }
}

extern "C" void kernel_launch(void* const* d_in, const int* in_sizes, int n_in,
                              void* d_out, int out_size, void* d_ws, size_t ws_size,
                              hipStream_t stream) {
    const float* pts = (const float*)d_in[0];   // (4, 8192, 3)
    const float* tv  = (const float*)d_in[1];   // (4, 1024, 3, 3)
    float* out = (float*)d_out;                 // (4, 8192)
    float4* pre = (float4*)d_ws;                // 4096 * 6 float4 = 384 KB

    rast_pre<<<16, 256, 0, stream>>>(tv, pre);
    rast_main<<<512, 256, 0, stream>>>(pts, pre, out);
}

// Round 2
// 111.087 us; speedup vs baseline: 1.1159x; 1.1159x over previous
//
#include <hip/hip_runtime.h>
#include <hip/hip_bf16.h>

#define ALPHA 100.0f

// Per-triangle precomputed invariants: 6 x float4 = 96 B
//  q0: v0.xyz, dt  (dt = area-OK ? max(area2,1e-12) : -1  -> folds flag into u+v test)
//  q1: e0.xyz, dot00
//  q2: e1.xyz, dot11
//  q3: nn.xyz (n * rsqrt(max(area2,1e-12))),  dot01
//  q4: inv00, inv11, c12(=dot00-dot01), invab
//  q5: abab(=dot00-2dot01+dot11), 0, 0, 0

__global__ __launch_bounds__(256) void rast_pre(const float* __restrict__ tv,
                                                float4* __restrict__ pre) {
    int i = blockIdx.x * 256 + threadIdx.x;   // 0..4095 triangles (4 batches x 1024)
    if (i >= 4096) return;
    const float* t = tv + (size_t)i * 9;
    float v0x = t[0], v0y = t[1], v0z = t[2];
    float v1x = t[3], v1y = t[4], v1z = t[5];
    float v2x = t[6], v2y = t[7], v2z = t[8];

    float e0x = v1x - v0x, e0y = v1y - v0y, e0z = v1z - v0z;
    float e1x = v2x - v0x, e1y = v2y - v0y, e1z = v2z - v0z;

    float nx = e0y * e1z - e0z * e1y;
    float ny = e0z * e1x - e0x * e1z;
    float nz = e0x * e1y - e0y * e1x;
    float area2 = nx * nx + ny * ny + nz * nz;

    float dot00 = e0x * e0x + e0y * e0y + e0z * e0z;
    float dot01 = e0x * e1x + e0y * e1y + e0z * e1z;
    float dot11 = e1x * e1x + e1y * e1y + e1z * e1z;

    float denom = fmaxf(area2, 1e-12f);
    double rs   = 1.0 / sqrt((double)denom);
    float nnx = (float)(nx * rs), nny = (float)(ny * rs), nnz = (float)(nz * rs);

    float inv00 = 1.0f / fmaxf(dot00, 1e-12f);
    float inv11 = 1.0f / fmaxf(dot11, 1e-12f);
    float abab  = dot00 - 2.0f * dot01 + dot11;
    float invab = 1.0f / fmaxf(abab, 1e-12f);
    float dt    = (area2 >= 4e-10f) ? denom : -1.0f;   // 4 * (1e-5)^2
    float c12   = dot00 - dot01;

    float4* q = pre + (size_t)i * 6;
    q[0] = make_float4(v0x, v0y, v0z, dt);
    q[1] = make_float4(e0x, e0y, e0z, dot00);
    q[2] = make_float4(e1x, e1y, e1z, dot11);
    q[3] = make_float4(nnx, nny, nnz, dot01);
    q[4] = make_float4(inv00, inv11, c12, invab);
    q[5] = make_float4(abab, 0.0f, 0.0f, 0.0f);
}

// Grid: 512 blocks x 1024 threads (16 waves).
// block -> (batch = blockIdx>>7, point-block = blockIdx&127 -> 64 points)
// lane (0..63) = point; wave (0..15) = 64-triangle chunk. 2 blocks/CU -> 32 waves/CU.
__global__ __launch_bounds__(1024) void rast_main(const float* __restrict__ pts,
                                                  const float4* __restrict__ pre,
                                                  float* __restrict__ out) {
    int b    = blockIdx.x >> 7;
    int pblk = blockIdx.x & 127;
    int lane = threadIdx.x & 63;
    int wave = __builtin_amdgcn_readfirstlane((int)(threadIdx.x >> 6));  // 0..15

    int point = pblk * 64 + lane;
    const float* pp = pts + ((size_t)b * 8192 + point) * 3;
    float px = pp[0], py = pp[1], pz = pp[2];

    const float4* tp = pre + ((size_t)b * 1024 + (size_t)wave * 64) * 6;

    float dmin = 3.4e38f;
#pragma unroll 2
    for (int k = 0; k < 64; ++k) {
        float4 q0 = tp[0];
        float4 q1 = tp[1];
        float4 q2 = tp[2];
        float4 q3 = tp[3];
        float4 q4 = tp[4];
        float4 q5 = tp[5];
        tp += 6;

        float dx = px - q0.x, dy = py - q0.y, dz = pz - q0.z;
        float dd = dx * dx + dy * dy + dz * dz;
        float a0 = q1.x * dx + q1.y * dy + q1.z * dz;   // dot(e0, d)
        float a1 = q2.x * dx + q2.y * dy + q2.z * dz;   // dot(e1, d)
        float dn = q3.x * dx + q3.y * dy + q3.z * dz;   // dot(n_scaled, d)

        float dot00 = q1.w, dot11 = q2.w, dot01 = q3.w, dt = q0.w;
        float inv00 = q4.x, inv11 = q4.y, c12 = q4.z, invab = q4.w;
        float abab = q5.x;

        // inside test, unnormalized: U>=0 && V>=0 && U+V<=dt  (dt=-1 kills degenerate)
        float U = dot11 * a0 - dot01 * a1;
        float V = dot00 * a1 - dot01 * a0;
        float m3 = fminf(fminf(U, V), dt - (U + V));    // v_min3
        float plane = dn * dn;

        float a02 = a0 + a0;
        float t1 = fminf(fmaxf(a0 * inv00, 0.0f), 1.0f);   // v_med3
        float s1 = dd + t1 * (t1 * dot00 - a02);
        float a12 = a1 + a1;
        float t2 = fminf(fmaxf(a1 * inv11, 0.0f), 1.0f);
        float s2 = dd + t2 * (t2 * dot11 - a12);
        float pab  = c12 + a1 - a0;            // dot(p-v1, v2-v1)
        float papa = (dd - a02) + dot00;       // |p-v1|^2
        float t3 = fminf(fmaxf(pab * invab, 0.0f), 1.0f);
        float s3 = papa + t3 * (t3 * abab - (pab + pab));

        float edge = fminf(fminf(s1, s2), s3);  // v_min3
        float r = (m3 >= 0.0f) ? plane : edge;
        dmin = fminf(dmin, r);
    }

    __shared__ float red[1024];
    red[threadIdx.x] = dmin;
    __syncthreads();
    if (threadIdx.x < 64) {
        float m = red[threadIdx.x];
#pragma unroll
        for (int w = 1; w < 16; ++w) m = fminf(m, red[w * 64 + threadIdx.x]);
        out[(size_t)b * 8192 + pblk * 64 + threadIdx.x] = __expf(-ALPHA * m);
    }
}

extern "C" void kernel_launch(void* const* d_in, const int* in_sizes, int n_in,
                              void* d_out, int out_size, void* d_ws, size_t ws_size,
                              hipStream_t stream) {
    const float* pts = (const float*)d_in[0];   // (4, 8192, 3)
    const float* tv  = (const float*)d_in[1];   // (4, 1024, 3, 3)
    float* out = (float*)d_out;                 // (4, 8192)
    float4* pre = (float4*)d_ws;                // 4096 * 6 float4 = 384 KB

    rast_pre<<<16, 256, 0, stream>>>(tv, pre);
    rast_main<<<512, 1024, 0, stream>>>(pts, pre, out);
}